// Round 8
// baseline (264.506 us; speedup 1.0000x reference)
//
#include <hip/hip_runtime.h>
#include <hip/hip_bf16.h>

// MultiAgentSEPSNetwork: A=8 agents, E=4096, O=256, H1=H2=1024, H3=512, S=4.
// M = A*E = 32768 rows. Only the seps_idx-selected net per agent is computed.
//
// R16: R13-R15 showed barrier/pin shaving converges at ~67us L2 (MfmaUtil
// 41%); the residual is the per-tile vmcnt(0) drain: all 8 DMAs target the
// next tile, issued mid-tile (~1000cyc cover) vs HBM latency ~900 -> one
// straggler stalls its wave, the barrier serializes the block. Fix = the
// m201/m218 counted-vmcnt flight pattern (the one template element never
// yet working here; m218: counted-vs-drain0 = +38..73%):
//  - K-half ring: 4 LDS units of {A 256x32 | B 256x32} = 32KB, 128KB total.
//  - stage half p+3 during half p (4 DMAs/wave); at each half boundary
//    VMCNT(8) retires ONLY the oldest half (2 halves stay in flight);
//    issue-to-retire cover ~3 half-periods (~4200cyc >> HBM 900).
//    vmcnt(4)/(0) only for the last two halves.
//  - 64B LDS rows (R9's conflict trap) fixed by layout
//    LDS[r][s16] = G[r][s16 ^ ((r>>1)&3)] via pre-swizzled per-lane global
//    source (LDS dest linear, rule 21). Read slot = quad ^ ((l16>>1)&3)
//    (lane-constant); bank audit: 2 lanes per 8-group (pairs l16/l16+8) =
//    same zero-conflict class as the proven chunk^(l16&7) pattern.
//  - barrier per half (2/tile) with SB0 both sides (R15 pins); no lgkm
//    drain (R14: fine-grained compiler waits win).
// Kept: 256x256 tile, 8 waves (2Mx4N), per-wave 128x64, XCD grid swizzle,
// fused prep, LDS-transpose epilogue (acc mapping unchanged).

typedef unsigned short u16;
typedef __bf16 bf16x8 __attribute__((ext_vector_type(8)));
typedef float floatx4 __attribute__((ext_vector_type(4)));

__device__ __forceinline__ u16 f2bf(float f) {
    union { float f; unsigned int u; } v; v.f = f;
    unsigned int u = v.u;
    return (u16)((u + 0x7FFFu + ((u >> 16) & 1u)) >> 16);
}

// global -> LDS direct DMA, 16 B/lane. LDS dest = wave-uniform base + lane*16.
__device__ __forceinline__ void load16(const void* g, void* l) {
    __builtin_amdgcn_global_load_lds(
        (const __attribute__((address_space(1))) void*)(unsigned long long)g,
        (__attribute__((address_space(3))) void*)(unsigned int)(unsigned long long)l,
        16, 0, 0);
}

// ---------------- fused prep: x->bf16 + 3 weight transposes ----------------
__global__ __launch_bounds__(256) void prep(
    const float* __restrict__ x, u16* __restrict__ xb,
    const float* __restrict__ W1, u16* __restrict__ w1t,
    const float* __restrict__ W2, u16* __restrict__ w2t,
    const float* __restrict__ W3, u16* __restrict__ w3t) {
    __shared__ float tile[32][33];
    int b = blockIdx.x;
    const int tid = threadIdx.x;
    if (b < 8192) {
        int i = (b * 256 + tid) * 4;
        float4 v = *(const float4*)(x + i);
        ushort4 o;
        o.x = f2bf(v.x); o.y = f2bf(v.y); o.z = f2bf(v.z); o.w = f2bf(v.w);
        *(ushort4*)(xb + i) = o;
        return;
    }
    b -= 8192;
    const float* src; u16* dst; int K, N, n0, k0, s;
    if (b < 1024) {                     // W1 [4][256][1024] -> [4][1024][256]
        s = b >> 8; int r = b & 255;
        K = 256; N = 1024; n0 = (r & 31) * 32; k0 = (r >> 5) * 32;
        src = W1; dst = w1t;
    } else if (b < 5120) {              // W2 [4][1024][1024] -> same^T
        b -= 1024; s = b >> 10; int r = b & 1023;
        K = 1024; N = 1024; n0 = (r & 31) * 32; k0 = (r >> 5) * 32;
        src = W2; dst = w2t;
    } else {                            // W3 [4][1024][512] -> [4][512][1024]
        b -= 5120; s = b >> 9; int r = b & 511;
        K = 1024; N = 512; n0 = (r & 15) * 32; k0 = (r >> 4) * 32;
        src = W3; dst = w3t;
    }
    src += (size_t)s * K * N;
    dst += (size_t)s * N * K;
    const int tx = tid & 31, ty = tid >> 5;
#pragma unroll
    for (int j = 0; j < 32; j += 8)
        tile[ty + j][tx] = src[(size_t)(k0 + ty + j) * N + (n0 + tx)];
    __syncthreads();
#pragma unroll
    for (int j = 0; j < 32; j += 8)
        dst[(size_t)(n0 + ty + j) * K + (k0 + tx)] = f2bf(tile[tx][ty + j]);
}

#define VMCNT(n) asm volatile("s_waitcnt vmcnt(" #n ")" ::: "memory")
#define SB0 __builtin_amdgcn_sched_barrier(0)

// ------- grouped GEMM: 256x256, K-half ring (4x32KB), counted vmcnt -------
// C[m,n] = act(A[M,K] @ Wt[s][N,K]^T + bias[s][N]);  s = seps[agent(m)]
// 512 thr = 8 waves (2M x 4N); per-wave C = 128x64 (acc 8x4); 16x16x32 MFMA.
// Half-unit p: {A[0..255][p*32..p*32+31] | B ...} as LDS[r][s]=G[r][s^((r>>1)&3)]
// at 16B granularity; 32 MFMA + 12 ds_read_b128 + 4 DMA per wave per half.
template <int K, int N, bool RELU, bool OUT_BF16>
__global__ __launch_bounds__(512, 2) void gemm_mlp(
    const u16* __restrict__ Amat, const u16* __restrict__ Wt,
    const float* __restrict__ bias, const int* __restrict__ seps,
    void* __restrict__ outp) {
    constexpr int P = K / 32;                  // number of K-halves
    constexpr int NNB = N / 256;               // n-blocks per m-stripe (4 or 2)
    constexpr int LNB = (NNB == 4) ? 2 : 1;
    extern __shared__ u16 lds[];               // 128 KB dynamic

    const int tid = threadIdx.x;
    const int wave = tid >> 6, lane = tid & 63;
    const int wm = wave >> 2, wn = wave & 3;
    const int quad = lane >> 4, l16 = lane & 15;

    // XCD swizzle: block i -> XCD i%8; all NNB n-blocks of one m-stripe are
    // dispatch-adjacent and share i%8 -> one XCD's L2 holds the A-stripe.
    const int bidx = blockIdx.x;
    const int t = bidx >> 3;
    const int mb = (t >> LNB) * 8 + (bidx & 7);
    const int nb = t & (NNB - 1);
    const int m0 = mb * 256, n0 = nb * 256;

    const int s = seps[m0 >> 12];              // 4096 rows per agent
    const u16* Ab = Amat + (size_t)m0 * K;
    const u16* Bb = Wt + ((size_t)s * N + n0) * K;

    // ---- staging lane geometry (pre-swizzled global source) ----
    // DMA d = wave*2+j covers LDS addr16 [64d,64d+63] of a unit:
    // lane L -> r = 16d + (L>>2), s16 = L&3, global 8-elem chunk
    // g = (L&3) ^ ((L>>3)&3)  => LDS[r][s16] = G[r][s16 ^ ((r>>1)&3)].
    const int srow = (wave << 5) + (lane >> 2);            // + j*16
    const int gsw = (((lane & 3) ^ ((lane >> 3) & 3)) << 3);
    const u16* gA = Ab + (size_t)srow * K + gsw;
    const u16* gB = Bb + (size_t)srow * K + gsw;
    // LDS dest (u16): slot*16384 + wave*1024 + j*512 (+8192 for B)
    const unsigned lw = (unsigned)(wave << 10);

    auto STAGE = [&](int p) {
        u16* ub = &lds[(p & 3) << 14];
        const int kо = p << 5;                 // k-offset = p*32 elems
#pragma unroll
        for (int j = 0; j < 2; ++j) {
            load16(gA + (size_t)(j << 4) * K + kо, ub + lw + (j << 9));
            load16(gB + (size_t)(j << 4) * K + kо, ub + 8192 + lw + (j << 9));
        }
    };

    // ---- fragment read bases (u16): addr = r*32 + s16*8, slot base added ----
    // read slot s16 = quad ^ ((r>>1)&3) = quad ^ ((l16>>1)&3)  (lane-const)
    const int sA = (quad ^ ((l16 >> 1) & 3)) << 3;
    const int a0 = (((wm << 7) + l16) << 5) + sA;          // A rows wm*128+
    const int b0 = 8192 + (((wn << 6) + l16) << 5) + sA;   // B rows wn*64+

    floatx4 acc[8][4];
#pragma unroll
    for (int i = 0; i < 8; ++i)
#pragma unroll
        for (int j = 0; j < 4; ++j) acc[i][j] = (floatx4){0.f, 0.f, 0.f, 0.f};

    // prologue: stage halves 0,1,2 (12 DMAs/wave in flight).
    STAGE(0); STAGE(1); STAGE(2);

    bf16x8 af[8], bf[4];

#pragma unroll 1
    for (int p = 0; p < P; ++p) {
        // retire ONLY the oldest half's 4 DMAs; 2 halves stay in flight.
        if (p <= P - 3)      { VMCNT(8); }
        else if (p == P - 2) { VMCNT(4); }
        else                 { VMCNT(0); }
        SB0;                                   // pin prev MFMAs above barrier
        __builtin_amdgcn_s_barrier();
        SB0;                                   // no hoisting above barrier

        const u16* buf = &lds[(p & 3) << 14];
        if (p + 3 < P) STAGE(p + 3);           // slot (p-1)&3: read last half,
                                               // consumed behind this barrier
        // 12 fragment reads (first MFMA's operands first)
        af[0] = *(const bf16x8*)&buf[a0];
#pragma unroll
        for (int nf = 0; nf < 4; ++nf)
            bf[nf] = *(const bf16x8*)&buf[b0 + (nf << 9)];
#pragma unroll
        for (int i = 1; i < 8; ++i)
            af[i] = *(const bf16x8*)&buf[a0 + (i << 9)];

        __builtin_amdgcn_s_setprio(1);
#pragma unroll
        for (int i = 0; i < 8; ++i)
#pragma unroll
            for (int nf = 0; nf < 4; ++nf)
                acc[i][nf] = __builtin_amdgcn_mfma_f32_16x16x32_bf16(
                    af[i], bf[nf], acc[i][nf], 0, 0, 0);
        __builtin_amdgcn_s_setprio(0);
    }
    __syncthreads();   // all LDS traffic done before epilogue reuse

    // ---- epilogue: 8 mf-phases, LDS transpose, coalesced stores ----
    float* eps = (float*)lds;                  // [32][268] f32 per phase
    constexpr int EW = 268;
    float bv[4];
#pragma unroll
    for (int nf = 0; nf < 4; ++nf)
        bv[nf] = bias[s * N + n0 + (wn << 6) + (nf << 4) + l16];

    const int rL = tid & 63;                   // float4 column slot
    const int rw = tid >> 6;                   // row base

#pragma unroll
    for (int mf = 0; mf < 8; ++mf) {
#pragma unroll
        for (int nf = 0; nf < 4; ++nf)
#pragma unroll
            for (int r = 0; r < 4; ++r) {
                float v = acc[mf][nf][r] + bv[nf];
                if (RELU) v = fmaxf(v, 0.0f);
                eps[((wm << 4) + (quad << 2) + r) * EW + (wn << 6) + (nf << 4) + l16] = v;
            }
        __syncthreads();
#pragma unroll
        for (int j = 0; j < 4; ++j) {
            const int er = rw + (j << 3);      // 0..31
            const int grow = m0 + ((er >> 4) << 7) + (mf << 4) + (er & 15);
            const float4 v = *(const float4*)&eps[er * EW + (rL << 2)];
            if (OUT_BF16) {
                ushort4 o;
                o.x = f2bf(v.x); o.y = f2bf(v.y); o.z = f2bf(v.z); o.w = f2bf(v.w);
                *(ushort4*)((u16*)outp + (size_t)grow * N + n0 + (rL << 2)) = o;
            } else {
                *(float4*)((float*)outp + (size_t)grow * N + n0 + (rL << 2)) = v;
            }
        }
        __syncthreads();
    }
}

extern "C" void kernel_launch(void* const* d_in, const int* in_sizes, int n_in,
                              void* d_out, int out_size, void* d_ws, size_t ws_size,
                              hipStream_t stream) {
    const float* x  = (const float*)d_in[0];
    const float* W1 = (const float*)d_in[1];
    const float* b1 = (const float*)d_in[2];
    const float* W2 = (const float*)d_in[3];
    const float* b2 = (const float*)d_in[4];
    const float* W3 = (const float*)d_in[5];
    const float* b3 = (const float*)d_in[6];
    const int* seps = (const int*)d_in[7];

    char* ws = (char*)d_ws;
    u16* w1t = (u16*)(ws);                    //  2 MB: [4][1024][256]
    u16* w2t = (u16*)(ws + (2ull << 20));     //  8 MB: [4][1024][1024]
    u16* w3t = (u16*)(ws + (10ull << 20));    //  4 MB: [4][512][1024]
    u16* xb  = (u16*)(ws + (14ull << 20));    // 16 MB: [32768][256]
    u16* h1  = (u16*)(ws + (30ull << 20));    // 64 MB: [32768][1024]
    u16* h2  = (u16*)(ws + (94ull << 20));    // 64 MB: [32768][1024]

    // 128 KB dynamic LDS opt-in (host-side, once).
    static int attr_once = []() {
        auto k1 = gemm_mlp<256, 1024, true, true>;
        auto k2 = gemm_mlp<1024, 1024, true, true>;
        auto k3 = gemm_mlp<1024, 512, false, false>;
        hipFuncSetAttribute(reinterpret_cast<const void*>(k1),
                            hipFuncAttributeMaxDynamicSharedMemorySize, 131072);
        hipFuncSetAttribute(reinterpret_cast<const void*>(k2),
                            hipFuncAttributeMaxDynamicSharedMemorySize, 131072);
        hipFuncSetAttribute(reinterpret_cast<const void*>(k3),
                            hipFuncAttributeMaxDynamicSharedMemorySize, 131072);
        return 0;
    }();
    (void)attr_once;

    prep<<<15360, 256, 0, stream>>>(x, xb, W1, w1t, W2, w2t, W3, w3t);

    // L1: [32768,256]@[256,1024]^T +b1, relu -> h1 (bf16)
    gemm_mlp<256, 1024, true, true><<<512, 512, 131072, stream>>>(xb, w1t, b1, seps, h1);
    // L2: [32768,1024]@[1024,1024]^T +b2, relu -> h2 (bf16)
    gemm_mlp<1024, 1024, true, true><<<512, 512, 131072, stream>>>(h1, w2t, b2, seps, h2);
    // L3: [32768,1024]@[1024,512]^T +b3 -> out (f32)
    gemm_mlp<1024, 512, false, false><<<256, 512, 131072, stream>>>(h2, w3t, b3, seps, d_out);
}